// Round 1
// 278.806 us; speedup vs baseline: 1.2268x; 1.2268x over previous
//
#include <hip/hip_runtime.h>
#include <hip/hip_bf16.h>

#define BB 4
#define NN 256           // nodes per batch
#define FD 128
#define HH 256
#define G3 384           // 3*F
#define STEPS 6
#define PO 896           // proj width: Ai[0:256) | Aj[256:512) | gh[512:896)
#define NODES (BB*NN)    // 1024

typedef __hip_bfloat16 bf16;

// ---- all scratch in device globals (d_ws untrusted) ----
__device__ float g_h[NODES*FD];
__device__ float g_proj[NODES*PO];
__device__ float g_S[NODES*HH];
__device__ float g_av2[NODES*2*NN];     // [grp][j][r][2] : (adj, valid)
__device__ float g_deg[NODES];
__device__ float g_mask[NODES];
__device__ float g_PT[FD*PO];           // [f][out]: W1i^T | W1j^T | Whh^T
__device__ float g_pbias[PO];
__device__ float g_w1e[HH];
__device__ float g_WihT[HH*G3];         // [h2][g]
__device__ float g_MT[HH*G3];           // [k][g] = (Wih@W2)[g][k]
__device__ float g_bv[G3];
__device__ float g_bihf[G3];

__device__ __forceinline__ float b2f(bf16 v){ return __bfloat162float(v); }
__device__ __forceinline__ float ldin(const void* p, int i, int isb){
  return isb ? b2f(((const bf16*)p)[i]) : ((const float*)p)[i];
}
__device__ __forceinline__ int probe_bf16(const void* mask){
  return ((const unsigned short*)mask)[0] == 0x3F80 ? 1 : 0;  // bf16 1.0 halfword
}

// ================= init A: everything input-only =================
// blocks [0,1024): adj row per node | [1024,1472): PT | [1472,1728): WihT
// [1728,2240): h | 2240: small vectors
__global__ __launch_bounds__(256) void k_init_a(
    const void* __restrict__ x, const void* __restrict__ adj,
    const void* __restrict__ mask, const void* __restrict__ W1,
    const void* __restrict__ b1, const void* __restrict__ Wih,
    const void* __restrict__ Whh, const void* __restrict__ bhh){
  int isb = probe_bf16(mask);
  int blk = blockIdx.x, tid = threadIdx.x;
  if (blk < 1024){                       // adj/valid/deg/mask for node = blk
    int node = blk, b = node >> 8, j = tid;
    float mi = ldin(mask, node, isb);
    float mj = ldin(mask, b*NN + j, isb);
    float a  = ldin(adj, node*NN + j, isb);
    float valid = (a > 0.f && mj > 0.f && mi > 0.f) ? 1.f : 0.f;
    int grp = node >> 2, r = node & 3;
    g_av2[grp*2048 + j*8 + r*2]     = a;
    g_av2[grp*2048 + j*8 + r*2 + 1] = valid;
    __shared__ float red[4];
    float s = valid;
    #pragma unroll
    for (int o = 32; o > 0; o >>= 1) s += __shfl_down(s, o, 64);
    if ((j & 63) == 0) red[j >> 6] = s;
    __syncthreads();
    if (j == 0){ g_deg[node] = red[0]+red[1]+red[2]+red[3]; g_mask[node] = mi; }
    return;
  }
  if (blk < 1472){                       // PT
    int i = (blk - 1024)*256 + tid;      // < 114688
    int f = i / PO, o = i % PO;
    float v;
    if (o < 256)       v = ldin(W1, o*257 + f, isb);
    else if (o < 512)  v = ldin(W1, (o-256)*257 + FD + f, isb);
    else               v = ldin(Whh, (o-512)*FD + f, isb);
    g_PT[i] = v;
    return;
  }
  if (blk < 1728){                       // WihT[h2][g] = Wih[g][h2]
    int h2 = blk - 1472;
    for (int g = tid; g < G3; g += 256)
      g_WihT[h2*G3 + g] = ldin(Wih, g*HH + h2, isb);
    return;
  }
  if (blk < 2240){                       // h init
    int i = (blk - 1728)*256 + tid;      // < 131072
    g_h[i] = ldin(x, i, isb);
    return;
  }
  // small vectors
  for (int i = tid; i < PO; i += 256){
    float v = 0.f;
    if (i < 256) v = ldin(b1, i, isb);
    else if (i >= 512) v = ldin(bhh, i-512, isb);
    g_pbias[i] = v;
  }
  for (int i = tid; i < HH; i += 256) g_w1e[i] = ldin(W1, i*257 + 256, isb);
  for (int i = tid; i < G3; i += 256) g_bihf[i] = 0.f;  // placeholder; set in MT
}

// ================= init B: MT = (Wih@W2)^T, bv, bihf =================
// Rewritten: previous version was a 1-outstanding-load dependent chain
// (VGPR=8, VALUBusy 1.9%, 88 us). Now: W2 column staged once in LDS
// (broadcast reads in the loop), bf16 probe hoisted out of the hot loop,
// 4 independent accumulators, unroll-8 -> 32 coalesced L2 loads in flight.
__global__ __launch_bounds__(384) void k_init_MT(const void* __restrict__ W2,
                                                 const void* __restrict__ b2,
                                                 const void* __restrict__ bih,
                                                 const void* __restrict__ mask){
  int isb = probe_bf16(mask);
  int k = blockIdx.x;     // 0..256 (k==256 -> bv + bihf)
  int g = threadIdx.x;    // 0..383
  __shared__ float col[HH];          // W2[:,k] (or b2)
  if (g < HH){
    col[g] = (k < HH) ? ldin(W2, g*HH + k, isb) : ldin(b2, g, isb);
  }
  __syncthreads();
  const float* wp = g_WihT + g;      // coalesced across threads, stride G3 per h2
  float a0 = 0.f, a1 = 0.f, a2 = 0.f, a3 = 0.f;
  #pragma unroll 8
  for (int h2 = 0; h2 < HH; h2 += 4){
    a0 = fmaf(col[h2+0], wp[(h2+0)*G3], a0);
    a1 = fmaf(col[h2+1], wp[(h2+1)*G3], a1);
    a2 = fmaf(col[h2+2], wp[(h2+2)*G3], a2);
    a3 = fmaf(col[h2+3], wp[(h2+3)*G3], a3);
  }
  float acc = (a0 + a1) + (a2 + a3);
  if (k < HH){
    g_MT[k*G3 + g] = acc;
  } else {
    g_bv[g] = acc;
    g_bihf[g] = ldin(bih, g, isb);
  }
}

// ================= per step: S[i][h] = sum_j relu(Ai+Aj+adj*w1e)*valid ==========
__global__ __launch_bounds__(512) void k_S(void){
  int grp = blockIdx.x;                 // 4 consecutive nodes (same batch)
  int tid = threadIdx.x;
  int hp = tid & 127;                   // h-pair: h = 2hp, 2hp+1
  int q  = tid >> 7;                    // j-quarter (wave-uniform)
  int n0 = grp*4, b = grp >> 6;
  __shared__ float avsh[NN*8];          // 8 KB [j][r][2]
  __shared__ float2 red[3][4][128];     // 12 KB partials q=1..3
  ((float4*)avsh)[tid] = ((const float4*)(g_av2 + grp*2048))[tid];
  float2 w12 = ((const float2*)g_w1e)[hp];
  float2 Ai2[4], acc[4];
  #pragma unroll
  for (int r = 0; r < 4; ++r){
    Ai2[r] = *(const float2*)(g_proj + (n0+r)*PO + 2*hp);
    acc[r] = make_float2(0.f, 0.f);
  }
  __syncthreads();
  const float* ajp = g_proj + (b*NN + q*64)*PO + 256 + 2*hp;
  const float4* avp = ((const float4*)avsh) + q*128;   // 2 float4 per j
  #pragma unroll 2
  for (int j = 0; j < 64; ++j){
    float2 a2 = *(const float2*)ajp; ajp += PO;
    float4 av01 = avp[2*j];
    float4 av23 = avp[2*j+1];
    float adv[4] = {av01.x, av01.z, av23.x, av23.z};
    float vmv[4] = {av01.y, av01.w, av23.y, av23.w};
    #pragma unroll
    for (int r = 0; r < 4; ++r){
      float vx = Ai2[r].x + a2.x;
      float vy = Ai2[r].y + a2.y;
      vx = fmaf(adv[r], w12.x, vx);
      vy = fmaf(adv[r], w12.y, vy);
      vx = fmaxf(vx, 0.f); vy = fmaxf(vy, 0.f);
      acc[r].x = fmaf(vx, vmv[r], acc[r].x);
      acc[r].y = fmaf(vy, vmv[r], acc[r].y);
    }
  }
  if (q){
    #pragma unroll
    for (int r = 0; r < 4; ++r) red[q-1][r][hp] = acc[r];
  }
  __syncthreads();
  if (q == 0){
    #pragma unroll
    for (int r = 0; r < 4; ++r){
      float2 s = acc[r];
      float2 p0 = red[0][r][hp], p1 = red[1][r][hp], p2 = red[2][r][hp];
      s.x += p0.x + p1.x + p2.x;
      s.y += p0.y + p1.y + p2.y;
      ((float2*)(g_S + (n0+r)*HH))[hp] = s;
    }
  }
}

// ================= fused: [GRU update] + [proj for next step] =================
__global__ __launch_bounds__(512) void k_up(void* __restrict__ out,
                                            const void* __restrict__ mask,
                                            int first, int last){
  int grp = blockIdx.x, tid = threadIdx.x, n0 = grp*4;
  __shared__ float Ssh[4][HH];        // 4 KB
  __shared__ float part[4][4][G3];    // 24 KB
  __shared__ float A[4][G3];          // 6 KB
  __shared__ float Bs[4][FD];         // 2 KB
  __shared__ float hsh[4][FD];        // 2 KB
  __shared__ float4 ppart[4][224];    // 14 KB

  if (!first){
    if (tid < 256) ((float4*)&Ssh[0][0])[tid] = ((const float4*)(g_S + n0*HH))[tid];
    __syncthreads();
    if (tid < 384){                    // gi GEMM, K split 4 ways
      int c = tid % 96, sub = tid / 96;
      int k0 = sub*64;
      float4 acc[4];
      #pragma unroll
      for (int r = 0; r < 4; ++r) acc[r] = make_float4(0.f,0.f,0.f,0.f);
      const float4* MT4 = (const float4*)g_MT;   // [256][96]
      #pragma unroll 2
      for (int k = 0; k < 64; ++k){
        float4 m = MT4[(k0+k)*96 + c];
        #pragma unroll
        for (int r = 0; r < 4; ++r){
          float s = Ssh[r][k0+k];
          acc[r].x = fmaf(s, m.x, acc[r].x);
          acc[r].y = fmaf(s, m.y, acc[r].y);
          acc[r].z = fmaf(s, m.z, acc[r].z);
          acc[r].w = fmaf(s, m.w, acc[r].w);
        }
      }
      #pragma unroll
      for (int r = 0; r < 4; ++r) ((float4*)&part[sub][r][0])[c] = acc[r];
    }
    __syncthreads();
    if (tid < 384){
      int g = tid;
      float bvg = g_bv[g], bihg = g_bihf[g];
      #pragma unroll
      for (int r = 0; r < 4; ++r){
        float gi = part[0][r][g] + part[1][r][g] + part[2][r][g] + part[3][r][g]
                 + g_deg[n0+r]*bvg + bihg;
        float gh = g_proj[(n0+r)*PO + 512 + g];
        if (g < 256) A[r][g] = gi + gh;
        else { A[r][g] = gi; Bs[r][g-256] = gh; }
      }
    }
    __syncthreads();
    if (tid < 128){
      int f = tid, isb = probe_bf16(mask);
      #pragma unroll
      for (int r = 0; r < 4; ++r){
        int node = n0 + r;
        float rr = 1.f/(1.f + __expf(-A[r][f]));
        float zz = 1.f/(1.f + __expf(-A[r][128+f]));
        float hn = Bs[r][f];
        float narg = A[r][256+f] + rr*hn;
        float e = __expf(2.f*narg);
        float nn = 1.f - 2.f/(e + 1.f);
        float hp_ = g_h[node*FD + f];
        float hv = (1.f - zz)*nn + zz*hp_;
        hv *= g_mask[node];
        hsh[r][f] = hv;
        g_h[node*FD + f] = hv;
        if (last){
          if (isb) ((bf16*)out)[node*FD + f] = __float2bfloat16(hv);
          else     ((float*)out)[node*FD + f] = hv;
        }
      }
    }
    __syncthreads();
  } else {
    if (tid < 128) ((float4*)&hsh[0][0])[tid] = ((const float4*)(g_h + n0*FD))[tid];
    __syncthreads();
  }

  if (!last){                          // proj for this step's h
    int c = tid & 255, fh = tid >> 8;  // f-split for occupancy
    float4 acc[4];
    #pragma unroll
    for (int r = 0; r < 4; ++r) acc[r] = make_float4(0.f,0.f,0.f,0.f);
    if (c < 224){
      const float4* PT4 = (const float4*)g_PT + fh*64*224 + c;
      #pragma unroll 4
      for (int f = 0; f < 64; ++f){
        float4 w = *PT4; PT4 += 224;
        #pragma unroll
        for (int r = 0; r < 4; ++r){
          float hv = hsh[r][fh*64 + f];
          acc[r].x = fmaf(hv, w.x, acc[r].x);
          acc[r].y = fmaf(hv, w.y, acc[r].y);
          acc[r].z = fmaf(hv, w.z, acc[r].z);
          acc[r].w = fmaf(hv, w.w, acc[r].w);
        }
      }
      if (fh == 1){
        #pragma unroll
        for (int r = 0; r < 4; ++r) ppart[r][c] = acc[r];
      }
    }
    __syncthreads();
    if (fh == 0 && c < 224){
      float4 pb = ((const float4*)g_pbias)[c];
      #pragma unroll
      for (int r = 0; r < 4; ++r){
        float4 p = ppart[r][c];
        float4 res;
        res.x = acc[r].x + p.x + pb.x;
        res.y = acc[r].y + p.y + pb.y;
        res.z = acc[r].z + p.z + pb.z;
        res.w = acc[r].w + p.w + pb.w;
        ((float4*)(g_proj + (n0+r)*PO))[c] = res;
      }
    }
  }
}

extern "C" void kernel_launch(void* const* d_in, const int* in_sizes, int n_in,
                              void* d_out, int out_size, void* d_ws, size_t ws_size,
                              hipStream_t stream){
  (void)in_sizes; (void)n_in; (void)out_size; (void)d_ws; (void)ws_size;
  const void* x    = d_in[0];
  const void* adj  = d_in[1];
  const void* mask = d_in[2];
  const void* W1   = d_in[3];
  const void* b1   = d_in[4];
  const void* W2   = d_in[5];
  const void* b2   = d_in[6];
  const void* Wih  = d_in[7];
  const void* bih  = d_in[8];
  const void* Whh  = d_in[9];
  const void* bhh  = d_in[10];

  k_init_a<<<2241, 256, 0, stream>>>(x, adj, mask, W1, b1, Wih, Whh, bhh);
  k_init_MT<<<HH + 1, 384, 0, stream>>>(W2, b2, bih, mask);

  for (int s = 0; s <= STEPS; ++s){
    k_up<<<NODES/4, 512, 0, stream>>>(d_out, mask, s == 0 ? 1 : 0,
                                      s == STEPS ? 1 : 0);
    if (s < STEPS) k_S<<<NODES/4, 512, 0, stream>>>();
  }
}

// Round 2
// 226.645 us; speedup vs baseline: 1.5091x; 1.2301x over previous
//
#include <hip/hip_runtime.h>
#include <hip/hip_bf16.h>

#define BB 4
#define NN 256           // nodes per batch
#define FD 128
#define HH 256
#define G3 384           // 3*F
#define STEPS 6
#define PO 896           // proj width: Ai[0:256) | Aj[256:512) | gh[512:896)
#define NODES (BB*NN)    // 1024

typedef __hip_bfloat16 bf16;

// ---- all scratch in device globals (d_ws untrusted) ----
__device__ float g_h[NODES*FD];
__device__ float g_proj[2*NODES*PO];    // double-buffered: fused step kernel
__device__ float g_av2[NODES*2*NN];     // [grp][j][r][2] : (adj, valid)
__device__ float g_deg[NODES];
__device__ float g_mask[NODES];
__device__ float g_PT[FD*PO];           // [f][out]: W1i^T | W1j^T | Whh^T
__device__ float g_pbias[PO];
__device__ float g_w1e[HH];
__device__ float g_WihT[HH*G3];         // [h2][g]
__device__ float g_MT[HH*G3];           // [k][g] = (Wih@W2)[g][k]
__device__ float g_bv[G3];
__device__ float g_bihf[G3];

__device__ __forceinline__ float b2f(bf16 v){ return __bfloat162float(v); }
__device__ __forceinline__ float ldin(const void* p, int i, int isb){
  return isb ? b2f(((const bf16*)p)[i]) : ((const float*)p)[i];
}
__device__ __forceinline__ int probe_bf16(const void* mask){
  return ((const unsigned short*)mask)[0] == 0x3F80 ? 1 : 0;  // bf16 1.0 halfword
}

// ================= init A: everything input-only =================
// blocks [0,1024): adj row per node | [1024,1472): PT | [1472,1728): WihT
// [1728,2240): h | 2240: small vectors
__global__ __launch_bounds__(256) void k_init_a(
    const void* __restrict__ x, const void* __restrict__ adj,
    const void* __restrict__ mask, const void* __restrict__ W1,
    const void* __restrict__ b1, const void* __restrict__ Wih,
    const void* __restrict__ Whh, const void* __restrict__ bhh){
  int isb = probe_bf16(mask);
  int blk = blockIdx.x, tid = threadIdx.x;
  if (blk < 1024){                       // adj/valid/deg/mask for node = blk
    int node = blk, b = node >> 8, j = tid;
    float mi = ldin(mask, node, isb);
    float mj = ldin(mask, b*NN + j, isb);
    float a  = ldin(adj, node*NN + j, isb);
    float valid = (a > 0.f && mj > 0.f && mi > 0.f) ? 1.f : 0.f;
    int grp = node >> 2, r = node & 3;
    g_av2[grp*2048 + j*8 + r*2]     = a;
    g_av2[grp*2048 + j*8 + r*2 + 1] = valid;
    __shared__ float red[4];
    float s = valid;
    #pragma unroll
    for (int o = 32; o > 0; o >>= 1) s += __shfl_down(s, o, 64);
    if ((j & 63) == 0) red[j >> 6] = s;
    __syncthreads();
    if (j == 0){ g_deg[node] = red[0]+red[1]+red[2]+red[3]; g_mask[node] = mi; }
    return;
  }
  if (blk < 1472){                       // PT
    int i = (blk - 1024)*256 + tid;      // < 114688
    int f = i / PO, o = i % PO;
    float v;
    if (o < 256)       v = ldin(W1, o*257 + f, isb);
    else if (o < 512)  v = ldin(W1, (o-256)*257 + FD + f, isb);
    else               v = ldin(Whh, (o-512)*FD + f, isb);
    g_PT[i] = v;
    return;
  }
  if (blk < 1728){                       // WihT[h2][g] = Wih[g][h2]
    int h2 = blk - 1472;
    for (int g = tid; g < G3; g += 256)
      g_WihT[h2*G3 + g] = ldin(Wih, g*HH + h2, isb);
    return;
  }
  if (blk < 2240){                       // h init
    int i = (blk - 1728)*256 + tid;      // < 131072
    g_h[i] = ldin(x, i, isb);
    return;
  }
  // small vectors
  for (int i = tid; i < PO; i += 256){
    float v = 0.f;
    if (i < 256) v = ldin(b1, i, isb);
    else if (i >= 512) v = ldin(bhh, i-512, isb);
    g_pbias[i] = v;
  }
  for (int i = tid; i < HH; i += 256) g_w1e[i] = ldin(W1, i*257 + 256, isb);
  for (int i = tid; i < G3; i += 256) g_bihf[i] = 0.f;  // placeholder; set in MT
}

// ================= init B: MT = (Wih@W2)^T, bv, bihf =================
// W2 column staged once in LDS (broadcast reads), probe hoisted, 4 independent
// accumulators, unroll-8 -> many coalesced L2 loads in flight.
__global__ __launch_bounds__(384) void k_init_MT(const void* __restrict__ W2,
                                                 const void* __restrict__ b2,
                                                 const void* __restrict__ bih,
                                                 const void* __restrict__ mask){
  int isb = probe_bf16(mask);
  int k = blockIdx.x;     // 0..256 (k==256 -> bv + bihf)
  int g = threadIdx.x;    // 0..383
  __shared__ float col[HH];          // W2[:,k] (or b2)
  if (g < HH){
    col[g] = (k < HH) ? ldin(W2, g*HH + k, isb) : ldin(b2, g, isb);
  }
  __syncthreads();
  const float* wp = g_WihT + g;      // coalesced across threads, stride G3 per h2
  float a0 = 0.f, a1 = 0.f, a2 = 0.f, a3 = 0.f;
  #pragma unroll 8
  for (int h2 = 0; h2 < HH; h2 += 4){
    a0 = fmaf(col[h2+0], wp[(h2+0)*G3], a0);
    a1 = fmaf(col[h2+1], wp[(h2+1)*G3], a1);
    a2 = fmaf(col[h2+2], wp[(h2+2)*G3], a2);
    a3 = fmaf(col[h2+3], wp[(h2+3)*G3], a3);
  }
  float acc = (a0 + a1) + (a2 + a3);
  if (k < HH){
    g_MT[k*G3 + g] = acc;
  } else {
    g_bv[g] = acc;
    g_bihf[g] = ldin(bih, g, isb);
  }
}

// ================= fused per-step kernel =================
// [S reduce over j] + [gi GEMM] + [GRU update] + [proj for next step]
// Cross-block hazard (S reads all nodes' Aj while proj writes own rows) is
// removed by double-buffering g_proj: read roff buffer (previous launch),
// write woff buffer. Kernel boundaries order everything else.
// LDS: S-phase scratch (20 KB) overlaid with GEMM-phase scratch (46 KB).
__global__ __launch_bounds__(512) void k_step(void* __restrict__ out,
                                              const void* __restrict__ mask,
                                              int first, int last,
                                              int roff, int woff){
  int grp = blockIdx.x, tid = threadIdx.x, n0 = grp*4;
  __shared__ __align__(16) float Ssh[4][HH];   // 4 KB, S result
  __shared__ __align__(16) float hsh[4][FD];   // 2 KB
  __shared__ __align__(16) char uni[47104];    // 46 KB overlay
  float*  avsh  = (float*)uni;                          // [0,8192)    S phase
  float2 (*red)[4][128]  = (float2 (*)[4][128])(uni + 8192);   // [8192,20480) S phase
  float  (*part)[4][G3]  = (float  (*)[4][G3])uni;             // [0,24576)   gi GEMM
  float  (*Aa)[G3]       = (float  (*)[G3])(uni + 24576);      // [24576,30720)
  float  (*Bs)[FD]       = (float  (*)[FD])(uni + 30720);      // [30720,32768)
  float4 (*ppart)[224]   = (float4 (*)[224])(uni + 32768);     // [32768,47104) proj
  const float* projr = g_proj + roff;
  float*       projw = g_proj + woff;

  if (!first){
    // ---------- S phase: S[i][h] = sum_j relu(Ai+Aj+adj*w1e)*valid ----------
    int hp = tid & 127;                 // h-pair: h = 2hp, 2hp+1
    int q  = tid >> 7;                  // j-quarter (wave-uniform)
    int b = grp >> 6;
    ((float4*)avsh)[tid] = ((const float4*)(g_av2 + grp*2048))[tid];
    float2 w12 = ((const float2*)g_w1e)[hp];
    float2 Ai2[4], acc2[4];
    #pragma unroll
    for (int r = 0; r < 4; ++r){
      Ai2[r] = *(const float2*)(projr + (n0+r)*PO + 2*hp);
      acc2[r] = make_float2(0.f, 0.f);
    }
    __syncthreads();
    const float* ajp = projr + (b*NN + q*64)*PO + 256 + 2*hp;
    const float4* avp = ((const float4*)avsh) + q*128;   // 2 float4 per j
    #pragma unroll 4
    for (int j = 0; j < 64; ++j){
      float2 a2 = *(const float2*)ajp; ajp += PO;
      float4 av01 = avp[2*j];
      float4 av23 = avp[2*j+1];
      float adv[4] = {av01.x, av01.z, av23.x, av23.z};
      float vmv[4] = {av01.y, av01.w, av23.y, av23.w};
      #pragma unroll
      for (int r = 0; r < 4; ++r){
        float vx = Ai2[r].x + a2.x;
        float vy = Ai2[r].y + a2.y;
        vx = fmaf(adv[r], w12.x, vx);
        vy = fmaf(adv[r], w12.y, vy);
        vx = fmaxf(vx, 0.f); vy = fmaxf(vy, 0.f);
        acc2[r].x = fmaf(vx, vmv[r], acc2[r].x);
        acc2[r].y = fmaf(vy, vmv[r], acc2[r].y);
      }
    }
    if (q){
      #pragma unroll
      for (int r = 0; r < 4; ++r) red[q-1][r][hp] = acc2[r];
    }
    __syncthreads();
    if (q == 0){
      #pragma unroll
      for (int r = 0; r < 4; ++r){
        float2 s = acc2[r];
        float2 p0 = red[0][r][hp], p1 = red[1][r][hp], p2 = red[2][r][hp];
        s.x += p0.x + p1.x + p2.x;
        s.y += p0.y + p1.y + p2.y;
        ((float2*)&Ssh[r][0])[hp] = s;
      }
    }
    __syncthreads();                    // S done; part may now overwrite avsh/red

    // ---------- gi GEMM: part = Ssh @ MT (K split 4 ways) ----------
    if (tid < 384){
      int c = tid % 96, sub = tid / 96;
      int k0 = sub*64;
      float4 acc[4];
      #pragma unroll
      for (int r = 0; r < 4; ++r) acc[r] = make_float4(0.f,0.f,0.f,0.f);
      const float4* MT4 = (const float4*)g_MT;   // [256][96]
      #pragma unroll 4
      for (int k = 0; k < 64; ++k){
        float4 m = MT4[(k0+k)*96 + c];
        #pragma unroll
        for (int r = 0; r < 4; ++r){
          float s = Ssh[r][k0+k];
          acc[r].x = fmaf(s, m.x, acc[r].x);
          acc[r].y = fmaf(s, m.y, acc[r].y);
          acc[r].z = fmaf(s, m.z, acc[r].z);
          acc[r].w = fmaf(s, m.w, acc[r].w);
        }
      }
      #pragma unroll
      for (int r = 0; r < 4; ++r) ((float4*)&part[sub][r][0])[c] = acc[r];
    }
    __syncthreads();
    if (tid < 384){
      int g = tid;
      float bvg = g_bv[g], bihg = g_bihf[g];
      #pragma unroll
      for (int r = 0; r < 4; ++r){
        float gi = part[0][r][g] + part[1][r][g] + part[2][r][g] + part[3][r][g]
                 + g_deg[n0+r]*bvg + bihg;
        float gh = projr[(n0+r)*PO + 512 + g];
        if (g < 256) Aa[r][g] = gi + gh;
        else { Aa[r][g] = gi; Bs[r][g-256] = gh; }
      }
    }
    __syncthreads();
    // ---------- GRU ----------
    if (tid < 128){
      int f = tid, isb = probe_bf16(mask);
      #pragma unroll
      for (int r = 0; r < 4; ++r){
        int node = n0 + r;
        float rr = 1.f/(1.f + __expf(-Aa[r][f]));
        float zz = 1.f/(1.f + __expf(-Aa[r][128+f]));
        float hn = Bs[r][f];
        float narg = Aa[r][256+f] + rr*hn;
        float e = __expf(2.f*narg);
        float nn = 1.f - 2.f/(e + 1.f);
        float hp_ = g_h[node*FD + f];
        float hv = (1.f - zz)*nn + zz*hp_;
        hv *= g_mask[node];
        hsh[r][f] = hv;
        g_h[node*FD + f] = hv;
        if (last){
          if (isb) ((bf16*)out)[node*FD + f] = __float2bfloat16(hv);
          else     ((float*)out)[node*FD + f] = hv;
        }
      }
    }
    __syncthreads();
  } else {
    if (tid < 128) ((float4*)&hsh[0][0])[tid] = ((const float4*)(g_h + n0*FD))[tid];
    __syncthreads();
  }

  if (!last){                          // proj for this step's h -> write buffer
    int c = tid & 255, fh = tid >> 8;  // f-split for occupancy
    float4 acc[4];
    #pragma unroll
    for (int r = 0; r < 4; ++r) acc[r] = make_float4(0.f,0.f,0.f,0.f);
    if (c < 224){
      const float4* PT4 = (const float4*)g_PT + fh*64*224 + c;
      #pragma unroll 4
      for (int f = 0; f < 64; ++f){
        float4 w = *PT4; PT4 += 224;
        #pragma unroll
        for (int r = 0; r < 4; ++r){
          float hv = hsh[r][fh*64 + f];
          acc[r].x = fmaf(hv, w.x, acc[r].x);
          acc[r].y = fmaf(hv, w.y, acc[r].y);
          acc[r].z = fmaf(hv, w.z, acc[r].z);
          acc[r].w = fmaf(hv, w.w, acc[r].w);
        }
      }
      if (fh == 1){
        #pragma unroll
        for (int r = 0; r < 4; ++r) ppart[r][c] = acc[r];
      }
    }
    __syncthreads();
    if (fh == 0 && c < 224){
      float4 pb = ((const float4*)g_pbias)[c];
      #pragma unroll
      for (int r = 0; r < 4; ++r){
        float4 p = ppart[r][c];
        float4 res;
        res.x = acc[r].x + p.x + pb.x;
        res.y = acc[r].y + p.y + pb.y;
        res.z = acc[r].z + p.z + pb.z;
        res.w = acc[r].w + p.w + pb.w;
        ((float4*)(projw + (n0+r)*PO))[c] = res;
      }
    }
  }
}

extern "C" void kernel_launch(void* const* d_in, const int* in_sizes, int n_in,
                              void* d_out, int out_size, void* d_ws, size_t ws_size,
                              hipStream_t stream){
  (void)in_sizes; (void)n_in; (void)out_size; (void)d_ws; (void)ws_size;
  const void* x    = d_in[0];
  const void* adj  = d_in[1];
  const void* mask = d_in[2];
  const void* W1   = d_in[3];
  const void* b1   = d_in[4];
  const void* W2   = d_in[5];
  const void* b2   = d_in[6];
  const void* Wih  = d_in[7];
  const void* bih  = d_in[8];
  const void* Whh  = d_in[9];
  const void* bhh  = d_in[10];

  k_init_a<<<2241, 256, 0, stream>>>(x, adj, mask, W1, b1, Wih, Whh, bhh);
  k_init_MT<<<HH + 1, 384, 0, stream>>>(W2, b2, bih, mask);

  for (int s = 0; s <= STEPS; ++s){
    int woff = (s & 1) * NODES * PO;          // write buffer for step s
    int roff = ((s + 1) & 1) * NODES * PO;    // read buffer (step s-1's write)
    k_step<<<NODES/4, 512, 0, stream>>>(d_out, mask, s == 0 ? 1 : 0,
                                        s == STEPS ? 1 : 0, roff, woff);
  }
}